// Round 12
// baseline (163.366 us; speedup 1.0000x reference)
//
#include <hip/hip_runtime.h>
#include <hip/hip_bf16.h>

#define NB 16
#define NS 2048
#define NE 256
#define NOUT 256
#define CAP 49152
#define RCAP 384  // per-block record cap (diag tile needs ~130)

typedef __attribute__((ext_vector_type(4))) float f32x4;
typedef __attribute__((ext_vector_type(8))) short s16x8;
typedef __attribute__((ext_vector_type(4))) short s16x4;
typedef unsigned int u32;
typedef unsigned long long u64;

__device__ __forceinline__ short bf16rn(float f) {
  unsigned u = __builtin_bit_cast(unsigned, f);
  u += 0x7FFFu + ((u >> 16) & 1u);
  return (short)(u >> 16);
}
__device__ __forceinline__ float bf16f(short s) {
  unsigned u = ((unsigned)(unsigned short)s) << 16;
  return __builtin_bit_cast(float, u);
}
__device__ __forceinline__ void gld_lds16(const void* g, void* l) {
  __builtin_amdgcn_global_load_lds(
      (const __attribute__((address_space(1))) u32*)g,
      (__attribute__((address_space(3))) u32*)l, 16, 0, 0);
}

// decode triangle tile index T in [0,136) -> (by, bx), by<=bx  (proven R2/R3)
__device__ __forceinline__ void tri_decode(int T, int& by, int& bx) {
  float f = sqrtf((float)(1089 - 8 * T));
  int b = (int)((33.0f - f) * 0.5f);
  if (b * (33 - b) / 2 > T) --b;
  else if ((b + 1) * (32 - b) / 2 <= T) ++b;
  by = b;
  bx = b + (T - b * (33 - b) / 2);
}

// ---------- prep: x f32 -> xbf bf16 + sq; block 0 zeroes counter ----------
__global__ __launch_bounds__(256) void prep_kernel(const float* __restrict__ x,
                                                   short* __restrict__ xbf,
                                                   float* __restrict__ sq,
                                                   u32* __restrict__ counter) {
  if (blockIdx.x == 0 && threadIdx.x == 0) *counter = 0u;
  int row = blockIdx.x * 4 + (threadIdx.x >> 6);
  int lane = threadIdx.x & 63;
  f32x4 v = *(const f32x4*)(x + (size_t)row * NE + lane * 4);
  s16x4 p;
  p[0] = bf16rn(v.x); p[1] = bf16rn(v.y); p[2] = bf16rn(v.z); p[3] = bf16rn(v.w);
  *(s16x4*)(xbf + (size_t)row * NE + lane * 4) = p;
  float s = v.x * v.x + v.y * v.y + v.z * v.z + v.w * v.w;
#pragma unroll
  for (int off = 32; off; off >>= 1) s += __shfl_xor(s, off);
  if (lane == 0) sq[row] = s;
}

// ---------- gram: 2176 = 16 batches x 136 triangle tiles; one tile/block ----
__global__ __launch_bounds__(256, 2) void gram_kernel(
    const short* __restrict__ xbf, const float* __restrict__ sqg,
    const float* __restrict__ alpha_p, float* __restrict__ rpart,
    u32* __restrict__ counter, u32* __restrict__ records) {
  __shared__ __align__(16) char smem[49152];  // 3 x 16KB B-chunk buffers
  __shared__ float cpart[128];
  __shared__ u32 rec_meta[RCAP];
  __shared__ float rec_e[RCAP];
  __shared__ u32 rec_cnt, rec_gbase;

  const int tid = threadIdx.x;
  const int lane = tid & 63;
  const int wid = tid >> 6;
  const int lrow = lane & 15, lq = lane >> 4;

  // XCD-chunk: 2176 = 8 * 272 -> 2 batches per XCD (xbf L2-resident, 1MB/batch)
  const int nbid = (blockIdx.x & 7) * 272 + (blockIdx.x >> 3);
  const int b = nbid / 136;
  int by, bx;
  tri_decode(nbid - b * 136, by, bx);
  const int rowbase = by * 128, colbase = bx * 128;
  const char* xc = (const char*)(xbf + (size_t)b * NS * NE);
  const float alpha = alpha_p[0];
  const float nal = -alpha;
  const float thresh = 17.328680f / alpha;  // 25*ln2/a: exp(w0) rounds to 1.0f

  if (tid == 0) rec_cnt = 0u;
  if (tid < 128) cpart[tid] = 0.f;

  // A fragments: direct global -> VGPR (rows linear 512B)
  s16x8 af[2][8];
#pragma unroll
  for (int m = 0; m < 2; ++m) {
    const char* arow = xc + (size_t)(rowbase + wid * 32 + m * 16 + lrow) * 512;
#pragma unroll
    for (int ks = 0; ks < 8; ++ks)
      af[m][ks] = *(const s16x8*)(arow + ks * 64 + lq * 16);
  }
  float rr[2][4], minrr = 3.4e38f;
#pragma unroll
  for (int m = 0; m < 2; ++m)
#pragma unroll
    for (int j = 0; j < 4; ++j) {
      rr[m][j] = sqg[b * NS + rowbase + wid * 32 + m * 16 + lq * 4 + j];
      minrr = fminf(minrr, rr[m][j]);
    }
  // drain A/rr so pipeline vmcnt literals below count ONLY stage loads
  asm volatile("s_waitcnt vmcnt(0)" ::: "memory");

  // B chunk c (64 k = 128 B of each of 128 cols) -> 16KB buffer
  const int swzl = ((lane & 7) * 16) ^ ((lane >> 3) << 4);
  auto stageB = [&](int c, char* buf) {
    const char* base =
        xc + (size_t)(colbase + wid * 32 + (lane >> 3)) * 512 + c * 128 + swzl;
    char* dst = buf + wid * 4096 + lane * 16;
#pragma unroll
    for (int i = 0; i < 4; ++i)
      gld_lds16(base + (size_t)(i * 8) * 512, dst + i * 1024);
  };

  f32x4 acc[2][8];
#pragma unroll
  for (int m = 0; m < 2; ++m)
#pragma unroll
    for (int n = 0; n < 8; ++n) acc[m][n] = (f32x4){0.f, 0.f, 0.f, 0.f};

  char* b0 = smem;
  char* b1 = smem + 16384;
  char* b2 = smem + 32768;
  stageB(0, b0);
  stageB(1, b1);
  // LDS init (rec_cnt, cpart) visible to all; stages stay in flight
  asm volatile("s_waitcnt lgkmcnt(0)" ::: "memory");
  __builtin_amdgcn_s_barrier();

  auto compute64 = [&](const char* buf, int c) {
#pragma unroll
    for (int ks = 0; ks < 2; ++ks) {
      s16x8 bv[8];
#pragma unroll
      for (int n = 0; n < 8; ++n) {
        int col = n * 16 + lrow;
        bv[n] = *(const s16x8*)(buf + col * 128 +
                                ((ks * 64 + lq * 16) ^ ((col & 7) << 4)));
      }
#pragma unroll
      for (int m = 0; m < 2; ++m)
#pragma unroll
        for (int n = 0; n < 8; ++n)
          acc[m][n] = __builtin_amdgcn_mfma_f32_16x16x32_bf16(
              af[m][c * 2 + ks], bv[n], acc[m][n], 0, 0, 0);
    }
  };

  // chunk 0: stage0 done (stage1 in flight) -> issue stage2 -> compute b0
  asm volatile("s_waitcnt vmcnt(4)" ::: "memory");
  __builtin_amdgcn_s_barrier();
  __builtin_amdgcn_sched_barrier(0);
  stageB(2, b2);
  compute64(b0, 0);
  // chunk 1: stage1 done -> issue stage3 into b0 (all waves past compute0)
  asm volatile("s_waitcnt vmcnt(4)" ::: "memory");
  __builtin_amdgcn_s_barrier();
  __builtin_amdgcn_sched_barrier(0);
  stageB(3, b0);
  compute64(b1, 1);
  // chunk 2
  asm volatile("s_waitcnt vmcnt(4)" ::: "memory");
  __builtin_amdgcn_s_barrier();
  __builtin_amdgcn_sched_barrier(0);
  compute64(b2, 2);
  // chunk 3 (drain)
  asm volatile("s_waitcnt vmcnt(0)" ::: "memory");
  __builtin_amdgcn_s_barrier();
  __builtin_amdgcn_sched_barrier(0);
  compute64(b0, 3);

  // ---------------- epilogue (one tile) ----------------
  float cc[8], mincc = 3.4e38f;
#pragma unroll
  for (int n = 0; n < 8; ++n) {
    cc[n] = sqg[b * NS + colbase + n * 16 + lrow];
    mincc = fminf(mincc, cc[n]);
  }
  float maxg = -3.4e38f;
#pragma unroll
  for (int m = 0; m < 2; ++m)
#pragma unroll
    for (int n = 0; n < 8; ++n)
#pragma unroll
      for (int j = 0; j < 4; ++j) maxg = fmaxf(maxg, acc[m][n][j]);

  float prs[2][4] = {{0.f, 0.f, 0.f, 0.f}, {0.f, 0.f, 0.f, 0.f}};
  float csum[8] = {0.f, 0.f, 0.f, 0.f, 0.f, 0.f, 0.f, 0.f};
  bool fast = (minrr + mincc - 2.f * maxg > thresh);
  if (__all(fast)) {
#pragma unroll
    for (int m = 0; m < 2; ++m)
#pragma unroll
      for (int j = 0; j < 4; ++j) prs[m][j] = 8.0f;  // 8 cols/lane, e==1.0f
#pragma unroll
    for (int n = 0; n < 8; ++n) csum[n] = 8.0f;      // 8 rows/lane
  } else {
#pragma unroll
    for (int m = 0; m < 2; ++m) {
#pragma unroll
      for (int j = 0; j < 4; ++j) {
        float rj = rr[m][j];
#pragma unroll
        for (int n = 0; n < 8; ++n) {
          float d2 = fmaxf(fmaf(-2.f, acc[m][n][j], rj + cc[n]), 0.f);
          float w0 = __expf(nal * d2);  // ==0 for far pairs
          float e = __expf(w0);         // ==1.0f exactly for far pairs
          prs[m][j] += e;
          csum[n] += e;
          if (d2 < thresh) {  // block-local record append (LDS atomic)
            int srow = rowbase + wid * 32 + m * 16 + lq * 4 + j;
            int tcol = colbase + n * 16 + lrow;
            u32 idx = atomicAdd(&rec_cnt, (by != bx) ? 2u : 1u);
            if (idx < RCAP) {
              rec_meta[idx] = ((u32)srow << 11) | (u32)tcol;
              rec_e[idx] = e;
            }
            if (by != bx && idx + 1 < RCAP) {  // mirror (t,s)
              rec_meta[idx + 1] = ((u32)tcol << 11) | (u32)srow;
              rec_e[idx + 1] = e;
            }
          }
        }
      }
    }
  }

  // row partials -> slot bx of strip by (plain stores)
#pragma unroll
  for (int m = 0; m < 2; ++m)
#pragma unroll
    for (int j = 0; j < 4; ++j) {
      float v = prs[m][j];
      v += __shfl_xor(v, 1);
      v += __shfl_xor(v, 2);
      v += __shfl_xor(v, 4);
      v += __shfl_xor(v, 8);
      if (lrow == 0)
        rpart[(size_t)(b * 16 + bx) * NS + rowbase + wid * 32 + m * 16 +
              lq * 4 + j] = v;
    }
  // col partials -> LDS combine across waves -> slot by of strip bx
  if (by != bx) {
#pragma unroll
    for (int n = 0; n < 8; ++n) {
      float v = csum[n];
      v += __shfl_xor(v, 16);
      v += __shfl_xor(v, 32);
      if (lq == 0) atomicAdd(&cpart[n * 16 + lrow], v);
    }
  }
  __syncthreads();  // cpart atomics + rec_cnt final
  if (by != bx && tid < 128)
    rpart[(size_t)(b * 16 + by) * NS + colbase + tid] = cpart[tid];

  // flush block-local records with ONE global atomic
  u32 cnt = rec_cnt;
  if (cnt > RCAP) cnt = RCAP;
  if (cnt) {
    if (tid == 0) rec_gbase = atomicAdd(counter, cnt);
    __syncthreads();
    u32 gb = rec_gbase;
    for (u32 i = tid; i < cnt; i += 256) {
      u32 g = gb + i;
      if (g < CAP) {
        records[2 * g] = ((u32)b << 22) | rec_meta[i];
        records[2 * g + 1] = __builtin_bit_cast(u32, rec_e[i]);
      }
    }
  }
}

// ---------- cfix: r = sum 16 slots -> rinv, tot, c[t] + corrections ----------
__global__ __launch_bounds__(512) void cfix_kernel(
    const float* __restrict__ rpart, const u32* __restrict__ counter,
    const u32* __restrict__ records, float* __restrict__ cws) {
  __shared__ float rinv_l[NS];  // 8KB
  __shared__ float c_l[NS];     // 8KB
  __shared__ float red[8];
  const int b = blockIdx.x;
  const int tid = threadIdx.x;
  const int lane = tid & 63;
  const int wv = tid >> 6;

  float inv_acc = 0.f;
#pragma unroll
  for (int k = 0; k < 4; ++k) {
    int row = k * 512 + tid;
    float r = 0.f;
#pragma unroll
    for (int sl = 0; sl < 16; ++sl)
      r += rpart[(size_t)(16 * b + sl) * NS + row];
    float inv = 1.0f / r;
    rinv_l[row] = inv;
    inv_acc += inv;
  }
#pragma unroll
  for (int off = 32; off; off >>= 1) inv_acc += __shfl_xor(inv_acc, off);
  if (lane == 0) red[wv] = inv_acc;
  __syncthreads();
  float tot = 0.f;
#pragma unroll
  for (int g = 0; g < 8; ++g) tot += red[g];
#pragma unroll
  for (int k = 0; k < 4; ++k) c_l[k * 512 + tid] = tot;
  __syncthreads();

  u32 cnt = *counter;
  if (cnt > CAP) cnt = CAP;
  for (u32 i = tid; i < cnt; i += 512) {
    u32 meta = records[2 * i];
    if ((int)(meta >> 22) != b) continue;
    float e = __builtin_bit_cast(float, records[2 * i + 1]);
    int s = (meta >> 11) & 2047, t = meta & 2047;
    atomicAdd(&c_l[t], (e - 1.0f) * rinv_l[s]);
  }
  __syncthreads();
#pragma unroll
  for (int k = 0; k < 4; ++k) {
    int t = k * 512 + tid;
    cws[(size_t)b * NS + t] = c_l[t];
  }
}

// ---------- pooledp: partial pooled over 256-t slices; grid (8,16) ----------
__global__ __launch_bounds__(256) void pooledp_kernel(
    const short* __restrict__ xbf, const float* __restrict__ cws,
    float* __restrict__ pooled_part) {
  __shared__ float red[8 * 256];  // 8KB
  const int slice = blockIdx.x;
  const int b = blockIdx.y;
  const int t0 = slice * 256;
  const short* xb = xbf + ((size_t)b * NS + t0) * NE;
  const float* cb = cws + (size_t)b * NS + t0;
  const int g = threadIdx.x >> 5;
  const int e8 = (threadIdx.x & 31) * 8;
  float acc[8] = {0.f, 0.f, 0.f, 0.f, 0.f, 0.f, 0.f, 0.f};
#pragma unroll 4
  for (int tt = 0; tt < 32; ++tt) {
    int t = g + tt * 8;
    float cv = cb[t];
    s16x8 v = *(const s16x8*)(xb + (size_t)t * NE + e8);
#pragma unroll
    for (int j = 0; j < 8; ++j) acc[j] = fmaf(cv, bf16f(v[j]), acc[j]);
  }
#pragma unroll
  for (int j = 0; j < 8; ++j) red[g * 256 + e8 + j] = acc[j];
  __syncthreads();
  float s = 0.f;
#pragma unroll
  for (int g2 = 0; g2 < 8; ++g2) s += red[g2 * 256 + threadIdx.x];
  pooled_part[((size_t)b * 8 + slice) * NE + threadIdx.x] = s;
}

// ---------- out: pooled = sum parts / S; out = pooled @ W^T + bias ----------
__global__ __launch_bounds__(256) void out_kernel(
    const float* __restrict__ pooled_part, const float* __restrict__ W,
    const float* __restrict__ bias, float* __restrict__ out) {
  __shared__ float pl[NE];
  const int b = blockIdx.x, o = threadIdx.x;
  float s = 0.f;
#pragma unroll
  for (int sl = 0; sl < 8; ++sl)
    s += pooled_part[((size_t)b * 8 + sl) * NE + o];
  pl[o] = s * (1.0f / NS);
  __syncthreads();
  const f32x4* wr4 = (const f32x4*)(W + (size_t)o * NE);
  float a = bias[o];
#pragma unroll 8
  for (int e = 0; e < 64; ++e) {
    f32x4 w4 = wr4[e];
    a += pl[e * 4 + 0] * w4.x + pl[e * 4 + 1] * w4.y + pl[e * 4 + 2] * w4.z +
         pl[e * 4 + 3] * w4.w;
  }
  out[b * NOUT + o] = a;
}

extern "C" void kernel_launch(void* const* d_in, const int* in_sizes, int n_in,
                              void* d_out, int out_size, void* d_ws, size_t ws_size,
                              hipStream_t stream) {
  const float* x = (const float*)d_in[0];
  const float* alpha = (const float*)d_in[1];
  const float* W = (const float*)d_in[2];
  const float* bias = (const float*)d_in[3];
  float* out = (float*)d_out;

  u32* counter = (u32*)d_ws;                    // 32 u32 (pad)
  float* sq = (float*)(counter + 32);           // NB*NS
  float* rpart = sq + NB * NS;                  // 16*NB*NS (16 slots)
  u32* records = (u32*)(rpart + 16 * NB * NS);  // 2*CAP
  float* cws = (float*)(records + 2 * CAP);     // NB*NS
  float* pooled_part = cws + NB * NS;           // NB*8*NE
  short* xbf = (short*)(pooled_part + NB * 8 * NE);  // NB*NS*NE bf16

  prep_kernel<<<NB * NS / 4, 256, 0, stream>>>(x, xbf, sq, counter);
  gram_kernel<<<NB * 136, 256, 0, stream>>>(xbf, sq, alpha, rpart, counter,
                                            records);
  cfix_kernel<<<NB, 512, 0, stream>>>(rpart, counter, records, cws);
  pooledp_kernel<<<dim3(8, NB), 256, 0, stream>>>(xbf, cws, pooled_part);
  out_kernel<<<NB, 256, 0, stream>>>(pooled_part, W, bias, out);
}